// Round 6
// baseline (256.279 us; speedup 1.0000x reference)
//
#include <hip/hip_runtime.h>
#include <math.h>
#include <string.h>

#define NBATCH 16

typedef __attribute__((ext_vector_type(8))) short short8;
typedef __attribute__((ext_vector_type(4))) float floatx4;
#define MFMA16(a, b, c) __builtin_amdgcn_mfma_f32_16x16x32_bf16(a, b, c, 0, 0, 0)

__device__ __forceinline__ unsigned short f2bf(float f) {
  unsigned int u = __float_as_uint(f);
  unsigned int rounding = ((u >> 16) & 1u) + 0x7fffu;
  return (unsigned short)((u + rounding) >> 16);
}
__device__ __forceinline__ unsigned int packbf2(float a, float b) {
  return (unsigned int)f2bf(a) | ((unsigned int)f2bf(b) << 16);
}
__device__ __forceinline__ float bflo(unsigned int u) {
  return __uint_as_float(u << 16);
}
__device__ __forceinline__ float bfhi(unsigned int u) {
  return __uint_as_float(u & 0xffff0000u);
}
__device__ __forceinline__ float fast_tanh(float x) {
  float e = __expf(2.f * x);
  return 1.f - 2.f / (e + 1.f);
}

// ---------------------------------------------------------------------------
// weight prep: wb1 [9][64][64] bf16, wb2 [9][96][64] bf16, coef bf16.
// ---------------------------------------------------------------------------
__global__ void prep_weights(const float* __restrict__ w1,
                             const float* __restrict__ w2,
                             const float* __restrict__ coef,
                             unsigned short* __restrict__ wb1,
                             unsigned short* __restrict__ wb2,
                             unsigned short* __restrict__ coefb) {
  int i = blockIdx.x * 256 + threadIdx.x;
  if (i < 131072) coefb[i] = f2bf(coef[i]);
  if (i < 36864) {
    int kk = i / 4096, rem = i - kk * 4096;
    int oc = rem >> 6, ic = rem & 63;
    wb1[i] = f2bf(w1[(oc * 64 + ic) * 9 + kk]);
  }
  if (i < 55296) {
    int kk = i / 6144, rem = i - kk * 6144;
    int oc = rem >> 6, ic = rem & 63;
    wb2[i] = f2bf(w2[(oc * 64 + ic) * 9 + kk]);
  }
}

// ---------------------------------------------------------------------------
// x (fp32 NCHW) -> xb (bf16 NHWC), via LDS transpose. Block = (n, y) row.
// ---------------------------------------------------------------------------
__global__ __launch_bounds__(256) void xb_prep(const float* __restrict__ x,
                                               unsigned short* __restrict__ xb) {
  __shared__ float tile[64][65];
  const int t = threadIdx.x;
  const int y = blockIdx.x, n = blockIdx.y;
  const float* xn = x + (size_t)n * 64 * 4096 + y * 64;
#pragma unroll
  for (int it = 0; it < 16; ++it) {
    int idx = it * 256 + t;
    int c = idx >> 6, xx = idx & 63;
    tile[c][xx] = xn[c * 4096 + xx];
  }
  __syncthreads();
  const int xx = t >> 2, cq = t & 3;
  unsigned short* dst = xb + ((size_t)n * 4096 + y * 64 + xx) * 64;
#pragma unroll
  for (int jj = 0; jj < 2; ++jj) {
    int ch0 = cq * 16 + jj * 8;
    unsigned int p[4];
#pragma unroll
    for (int e = 0; e < 4; ++e)
      p[e] = packbf2(tile[ch0 + e * 2][xx], tile[ch0 + e * 2 + 1][xx]);
    *(uint4*)&dst[ch0] = make_uint4(p[0], p[1], p[2], p[3]);
  }
}

// ---------------------------------------------------------------------------
// Fused conv1+BN+tanh -> h (LDS only) -> conv2+BN+tanh -> bc (global, NHWC bf16)
// Block: 256 thr (4 waves), bc tile 16 wide x 8 tall. Grid (32, 16) = 512.
// x staged 20x12x64 bf16; h 10x18 px (padded to 192) x 64 in LDS.
// IMPORTANT: h halo pixels OUTSIDE the 64x64 image must be ZERO (conv2's
// zero-padding), not conv1 applied to zero-padded x.
// ---------------------------------------------------------------------------
__global__ __launch_bounds__(256) void fused_conv(
    const unsigned short* __restrict__ xb, const unsigned short* __restrict__ wb1,
    const unsigned short* __restrict__ wb2, const float* __restrict__ b1,
    const float* __restrict__ g1, const float* __restrict__ be1,
    const float* __restrict__ m1, const float* __restrict__ v1,
    const float* __restrict__ b2, const float* __restrict__ g2,
    const float* __restrict__ be2, const float* __restrict__ m2,
    const float* __restrict__ v2, unsigned short* __restrict__ bcg) {
  __shared__ unsigned short xls[240 * 72];  // [(xr*20+xc)][ic]
  __shared__ unsigned short hls[192 * 72];  // [hpx][oc]

  const int t = threadIdx.x;
  const int tile = blockIdx.x, n = blockIdx.y;
  const int x0 = (tile & 3) * 16, y0 = (tile >> 2) * 8;

  // stage x: rows y0-2..y0+9, cols x0-2..x0+17
  const unsigned short* xbn = xb + (size_t)n * 4096 * 64;
#pragma unroll
  for (int it = 0; it < 8; ++it) {
    int idx = it * 256 + t;  // 1920 total
    if (idx < 1920) {
      int pos = idx >> 3, u4 = idx & 7;
      int xr = pos / 20, xc = pos - xr * 20;
      int gy = y0 - 2 + xr, gx = x0 - 2 + xc;
      uint4 v = {0u, 0u, 0u, 0u};
      if ((unsigned)gy < 64u && (unsigned)gx < 64u)
        v = *(const uint4*)&xbn[((size_t)gy * 64 + gx) * 64 + u4 * 8];
      *(uint4*)&xls[pos * 72 + u4 * 8] = v;
    }
  }
  __syncthreads();

  const int lane = t & 63, w = t >> 6;
  const int wm = w & 1, wn = w >> 1;
  const int lm = lane & 15, lq = lane >> 4;

  // ---- phase 1: h = tanh(bn1(conv1(x))), M=192(180 used), N=64, K=576 ----
  int abase[6];
#pragma unroll
  for (int i = 0; i < 6; ++i) {
    int m = wm + 2 * i;
    int px = m * 16 + lm;
    if (px > 179) px = 179;
    int r = px / 18, c = px - r * 18;
    abase[i] = (r * 20 + c) * 72 + lq * 8;
  }
  floatx4 acc[6][2];
#pragma unroll
  for (int i = 0; i < 6; ++i)
#pragma unroll
    for (int u = 0; u < 2; ++u) acc[i][u] = floatx4{0.f, 0.f, 0.f, 0.f};

#pragma unroll
  for (int step = 0; step < 18; ++step) {
    const int off = step >> 1, kc = step & 1;
    const int di = off / 3, dj = off % 3;
    short8 b[2];
#pragma unroll
    for (int u = 0; u < 2; ++u)
      b[u] = *(const short8*)&wb1[((size_t)off * 64 + wn * 32 + u * 16 + lm) * 64 +
                                  kc * 32 + lq * 8];
#pragma unroll
    for (int i = 0; i < 6; ++i) {
      short8 a = *(const short8*)&xls[abase[i] + (di * 20 + dj) * 72 + kc * 32];
      acc[i][0] = MFMA16(a, b[0], acc[i][0]);
      acc[i][1] = MFMA16(a, b[1], acc[i][1]);
    }
  }
  {
    float sc[2], sh[2];
#pragma unroll
    for (int u = 0; u < 2; ++u) {
      int oc = wn * 32 + u * 16 + lm;
      sc[u] = g1[oc] * rsqrtf(v1[oc] + 1e-5f);
      sh[u] = (b1[oc] - m1[oc]) * sc[u] + be1[oc];
    }
#pragma unroll
    for (int i = 0; i < 6; ++i) {
      int px0 = (wm + 2 * i) * 16 + lq * 4;
#pragma unroll
      for (int u = 0; u < 2; ++u) {
        int oc = wn * 32 + u * 16 + lm;
#pragma unroll
        for (int r = 0; r < 4; ++r) {
          int px = px0 + r;
          int rh = px / 18, ch = px - rh * 18;
          int gy = y0 - 1 + rh, gx = x0 - 1 + ch;
          // h outside the image is ZERO (conv2 zero-padding semantics)
          bool valid = ((unsigned)gy < 64u) && ((unsigned)gx < 64u);
          float val = valid ? fast_tanh(acc[i][u][r] * sc[u] + sh[u]) : 0.f;
          hls[px * 72 + oc] = f2bf(val);
        }
      }
    }
  }
  __syncthreads();

  // ---- phase 2: bc = tanh(bn2(conv2(h))), M=128, N=96, K=576 ----
  int hbase[4];
#pragma unroll
  for (int i = 0; i < 4; ++i) {
    int opx = (wm + 2 * i) * 16 + lm;
    int br = opx >> 4, bcol = opx & 15;
    hbase[i] = (br * 18 + bcol) * 72 + lq * 8;
  }
  floatx4 acc2[4][3];
#pragma unroll
  for (int i = 0; i < 4; ++i)
#pragma unroll
    for (int u = 0; u < 3; ++u) acc2[i][u] = floatx4{0.f, 0.f, 0.f, 0.f};

#pragma unroll
  for (int step = 0; step < 18; ++step) {
    const int off = step >> 1, kc = step & 1;
    const int di = off / 3, dj = off % 3;
    short8 b[3];
#pragma unroll
    for (int u = 0; u < 3; ++u)
      b[u] = *(const short8*)&wb2[((size_t)off * 96 + wn * 48 + u * 16 + lm) * 64 +
                                  kc * 32 + lq * 8];
#pragma unroll
    for (int i = 0; i < 4; ++i) {
      short8 a = *(const short8*)&hls[hbase[i] + (di * 18 + dj) * 72 + kc * 32];
      acc2[i][0] = MFMA16(a, b[0], acc2[i][0]);
      acc2[i][1] = MFMA16(a, b[1], acc2[i][1]);
      acc2[i][2] = MFMA16(a, b[2], acc2[i][2]);
    }
  }
  {
    float sc[3], sh[3];
#pragma unroll
    for (int u = 0; u < 3; ++u) {
      int oc = wn * 48 + u * 16 + lm;
      sc[u] = g2[oc] * rsqrtf(v2[oc] + 1e-5f);
      sh[u] = (b2[oc] - m2[oc]) * sc[u] + be2[oc];
    }
    unsigned short* bcn = bcg + (size_t)n * 4096 * 96;
#pragma unroll
    for (int i = 0; i < 4; ++i) {
      int opx0 = (wm + 2 * i) * 16 + lq * 4;
#pragma unroll
      for (int u = 0; u < 3; ++u) {
        int oc = wn * 48 + u * 16 + lm;
#pragma unroll
        for (int r = 0; r < 4; ++r) {
          int opx = opx0 + r;
          int y = y0 + (opx >> 4), xx = x0 + (opx & 15);
          bcn[((size_t)y * 64 + xx) * 96 + oc] =
              f2bf(fast_tanh(acc2[i][u][r] * sc[u] + sh[u]));
        }
      }
    }
  }
}

// ---------------------------------------------------------------------------
// adconv v3: barrier-free. Block 256 thr (4 waves), 8x8 px tile, grid (64,16).
// Wave w owns px = w*16+lm, all 128 oc. Lane builds its own A-fragment:
// atoms[9][8] (f-half = lq&1) in regs; patches via broadcast ds_read_b64
// (c-quad per round, half-select by lq>>1); B streams from L2/L1.
// ---------------------------------------------------------------------------
__global__ __launch_bounds__(256) void adconv_final(
    const unsigned short* __restrict__ xb, const unsigned short* __restrict__ bc,
    const float* __restrict__ bases, const unsigned short* __restrict__ coefb,
    float* __restrict__ out) {
  __shared__ unsigned short xs[100 * 72];  // [pos][c], 14.4 KB

  const int t = threadIdx.x;
  const int tile = blockIdx.x, n = blockIdx.y;
  const int q0 = (tile & 7) * 8, p0 = (tile >> 3) * 8;

  float bs[54];
#pragma unroll
  for (int i = 0; i < 54; ++i) bs[i] = bases[i];

  // stage xs[pos][c] from xb NHWC (coalesced uint4)
  const unsigned short* xbn = xb + (size_t)n * 4096 * 64;
#pragma unroll
  for (int it = 0; it < 4; ++it) {
    int idx = it * 256 + t;  // 800 total
    if (idx < 800) {
      int pos = idx >> 3, u4 = idx & 7;
      int r = pos / 10, col = pos - r * 10;
      int gp = p0 - 1 + r, gq = q0 - 1 + col;
      uint4 v = {0u, 0u, 0u, 0u};
      if ((unsigned)gp < 64u && (unsigned)gq < 64u)
        v = *(const uint4*)&xbn[((size_t)gp * 64 + gq) * 64 + u4 * 8];
      *(uint4*)&xs[pos * 72 + u4 * 8] = v;
    }
  }

  const int lane = t & 63, w = t >> 6;
  const int lm = lane & 15, lq = lane >> 4;
  const int px = w * 16 + lm;
  const int qx = px >> 3, py = px & 7;
  const int fh = lq & 1;               // f-half
  const unsigned sh = (lq >> 1) * 16;  // c half-select shift

  // atoms[k][j] for f = fh*8+j, from bc global (bf16 NHWC)
  float at[9][8];
  {
    const unsigned short* bp =
        bc + ((size_t)n * 4096 + (q0 + qx) * 64 + (p0 + py)) * 96 + fh * 48;
    float bcv[48];
#pragma unroll
    for (int m = 0; m < 6; ++m) {
      uint4 v = *(const uint4*)(bp + m * 8);
      unsigned int uu[4] = {v.x, v.y, v.z, v.w};
#pragma unroll
      for (int e = 0; e < 4; ++e) {
        bcv[m * 8 + e * 2] = bflo(uu[e]);
        bcv[m * 8 + e * 2 + 1] = bfhi(uu[e]);
      }
    }
#pragma unroll
    for (int j = 0; j < 8; ++j)
#pragma unroll
      for (int k = 0; k < 9; ++k) {
        float a = 0.f;
#pragma unroll
        for (int tt = 0; tt < 6; ++tt)
          a = fmaf(bcv[j * 6 + tt], bs[tt * 9 + k], a);
        at[k][j] = a;
      }
  }

  // patch base addresses (shorts)
  int pa[9];
#pragma unroll
  for (int i = 0; i < 3; ++i)
#pragma unroll
    for (int j = 0; j < 3; ++j)
      pa[i * 3 + j] = ((py + i) * 10 + qx + j) * 72;

  // B base pointers per ntile
  const unsigned short* bptr[8];
#pragma unroll
  for (int u = 0; u < 8; ++u)
    bptr[u] = coefb + (size_t)(u * 16 + lm) * 1024 + lq * 8;

  __syncthreads();  // xs ready

  floatx4 acc[8];
#pragma unroll
  for (int u = 0; u < 8; ++u) acc[u] = floatx4{0.f, 0.f, 0.f, 0.f};

#pragma unroll
  for (int rd = 0; rd < 16; ++rd) {
    // patches: one b64 per pos gives the round's c-quad (broadcast across lq)
    uint2 q[9];
#pragma unroll
    for (int p = 0; p < 9; ++p) q[p] = *(const uint2*)&xs[pa[p] + rd * 4];
    float a0[8], a1[8];
#pragma unroll
    for (int j = 0; j < 8; ++j) { a0[j] = 0.f; a1[j] = 0.f; }
#pragma unroll
    for (int p = 0; p < 9; ++p) {
      float p0v = __uint_as_float((q[p].x >> sh) << 16);  // kc=0 patch
      float p1v = __uint_as_float((q[p].y >> sh) << 16);  // kc=1 patch
#pragma unroll
      for (int j = 0; j < 8; ++j) {
        a0[j] = fmaf(p0v, at[p][j], a0[j]);
        a1[j] = fmaf(p1v, at[p][j], a1[j]);
      }
    }
    short8 A0, A1;
    {
      unsigned int w0[4], w1[4];
#pragma unroll
      for (int e = 0; e < 4; ++e) {
        w0[e] = packbf2(a0[e * 2], a0[e * 2 + 1]);
        w1[e] = packbf2(a1[e * 2], a1[e * 2 + 1]);
      }
      uint4 t0 = make_uint4(w0[0], w0[1], w0[2], w0[3]);
      uint4 t1 = make_uint4(w1[0], w1[1], w1[2], w1[3]);
      A0 = *(short8*)&t0;
      A1 = *(short8*)&t1;
    }
#pragma unroll
    for (int u = 0; u < 8; ++u) {
      short8 b0 = *(const short8*)(bptr[u] + rd * 64);
      short8 b1 = *(const short8*)(bptr[u] + rd * 64 + 32);
      acc[u] = MFMA16(A0, b0, acc[u]);
      acc[u] = MFMA16(A1, b1, acc[u]);
    }
  }

  // direct stores: C/D reg-run is contiguous in p (fast axis)
  float* outn = out + (size_t)n * 128 * 4096;
  const int px0 = w * 16 + lq * 4;
  const int qxs = px0 >> 3, py0 = px0 & 7;
#pragma unroll
  for (int u = 0; u < 8; ++u) {
    int oc = u * 16 + lm;
    *(float4*)&outn[((size_t)oc * 64 + q0 + qxs) * 64 + p0 + py0] =
        make_float4(acc[u][0], acc[u][1], acc[u][2], acc[u][3]);
  }
}

// ---------------------------------------------------------------------------
extern "C" void kernel_launch(void* const* d_in, const int* in_sizes, int n_in,
                              void* d_out, int out_size, void* d_ws,
                              size_t ws_size, hipStream_t stream) {
  const float* x = (const float*)d_in[0];
  const float* conv1_w = (const float*)d_in[1];
  const float* conv1_b = (const float*)d_in[2];
  const float* bn1_g = (const float*)d_in[3];
  const float* bn1_b = (const float*)d_in[4];
  const float* bn1_m = (const float*)d_in[5];
  const float* bn1_v = (const float*)d_in[6];
  const float* conv2_w = (const float*)d_in[7];
  const float* conv2_b = (const float*)d_in[8];
  const float* bn2_g = (const float*)d_in[9];
  const float* bn2_b = (const float*)d_in[10];
  const float* bn2_m = (const float*)d_in[11];
  const float* bn2_v = (const float*)d_in[12];
  const float* bases = (const float*)d_in[13];
  const float* coef = (const float*)d_in[14];
  float* out = (float*)d_out;

  char* ws = (char*)d_ws;
  unsigned short* xbuf = (unsigned short*)(ws);             // 8,388,608 B
  unsigned short* bcb = (unsigned short*)(ws + 8388608);    // 12,582,912 B
  unsigned short* wb1 = (unsigned short*)(ws + 20971520);   // 73,728 B
  unsigned short* wb2 = (unsigned short*)(ws + 21045248);   // 110,592 B
  unsigned short* coefb = (unsigned short*)(ws + 21155840); // 262,144 B

  prep_weights<<<512, 256, 0, stream>>>(conv1_w, conv2_w, coef, wb1, wb2, coefb);
  xb_prep<<<dim3(64, NBATCH), 256, 0, stream>>>(x, xbuf);
  fused_conv<<<dim3(32, NBATCH), 256, 0, stream>>>(
      xbuf, wb1, wb2, conv1_b, bn1_g, bn1_b, bn1_m, bn1_v, conv2_b, bn2_g,
      bn2_b, bn2_m, bn2_v, bcb);
  adconv_final<<<dim3(64, NBATCH), 256, 0, stream>>>(xbuf, bcb, bases, coefb,
                                                     out);
}

// Round 7
// 188.441 us; speedup vs baseline: 1.3600x; 1.3600x over previous
//
#include <hip/hip_runtime.h>
#include <math.h>
#include <string.h>

#define NBATCH 16

typedef __attribute__((ext_vector_type(8))) short short8;
typedef __attribute__((ext_vector_type(4))) float floatx4;
#define MFMA16(a, b, c) __builtin_amdgcn_mfma_f32_16x16x32_bf16(a, b, c, 0, 0, 0)

__device__ __forceinline__ unsigned short f2bf(float f) {
  unsigned int u = __float_as_uint(f);
  unsigned int rounding = ((u >> 16) & 1u) + 0x7fffu;
  return (unsigned short)((u + rounding) >> 16);
}
__device__ __forceinline__ unsigned int packbf2(float a, float b) {
  return (unsigned int)f2bf(a) | ((unsigned int)f2bf(b) << 16);
}
__device__ __forceinline__ float bflo(unsigned int u) {
  return __uint_as_float(u << 16);
}
__device__ __forceinline__ float bfhi(unsigned int u) {
  return __uint_as_float(u & 0xffff0000u);
}
__device__ __forceinline__ float fast_tanh(float x) {
  float e = __expf(2.f * x);
  return 1.f - 2.f / (e + 1.f);
}

// ---------------------------------------------------------------------------
// weight prep -> MFMA-fragment-order ("swizzled") layouts, so every wave
// B-load is a contiguous 1KB global_load_dwordx4 (lane l reads frag*64+l).
//  coefswz: frag f = rd*1024 + kc*512 + u*64 + lane  (rd<16, kc<2, u<8)
//           holds coef[oc=u*16+lm][k=rd*64+kc*32+lq*8+j], j=0..7
//  w1swz:   f = off*512 + kc*256 + wn*128 + u*64 + lane (off<9,kc<2,wn<2,u<2)
//           holds w1[oc=wn*32+u*16+lm][ic=kc*32+lq*8+j][off]
//  w2swz:   f = off*768 + kc*384 + wn*192 + u*64 + lane (u<3)
//           holds w2[oc=wn*48+u*16+lm][ic=kc*32+lq*8+j][off]
// ---------------------------------------------------------------------------
__global__ void prep_weights(const float* __restrict__ w1,
                             const float* __restrict__ w2,
                             const float* __restrict__ coef,
                             unsigned short* __restrict__ w1swz,
                             unsigned short* __restrict__ w2swz,
                             unsigned short* __restrict__ coefswz) {
  int i = blockIdx.x * 256 + threadIdx.x;
  if (i < 131072) {
    int j = i & 7, f = i >> 3;
    int lane = f & 63;
    int u = (f >> 6) & 7;
    int kc = (f >> 9) & 1;
    int rd = f >> 10;
    int lm = lane & 15, lq = lane >> 4;
    int oc = u * 16 + lm;
    int k = rd * 64 + kc * 32 + lq * 8 + j;
    coefswz[i] = f2bf(coef[oc * 1024 + k]);
  }
  if (i < 36864) {
    int j = i & 7, f = i >> 3;
    int lane = f & 63;
    int u = (f >> 6) & 1;
    int wn = (f >> 7) & 1;
    int kc = (f >> 8) & 1;
    int off = f >> 9;
    int lm = lane & 15, lq = lane >> 4;
    int oc = wn * 32 + u * 16 + lm;
    int ic = kc * 32 + lq * 8 + j;
    w1swz[i] = f2bf(w1[(oc * 64 + ic) * 9 + off]);
  }
  if (i < 55296) {
    int j = i & 7, f = i >> 3;
    int lane = f & 63;
    int rem = f >> 6;
    int u = rem % 3;
    int rem2 = rem / 3;
    int wn = rem2 & 1;
    int kc = (rem2 >> 1) & 1;
    int off = rem2 >> 2;
    int lm = lane & 15, lq = lane >> 4;
    int oc = wn * 48 + u * 16 + lm;
    int ic = kc * 32 + lq * 8 + j;
    w2swz[i] = f2bf(w2[(oc * 64 + ic) * 9 + off]);
  }
}

// ---------------------------------------------------------------------------
// x (fp32 NCHW) -> xb (bf16 NHWC), via LDS transpose. Block = (n, y) row.
// ---------------------------------------------------------------------------
__global__ __launch_bounds__(256) void xb_prep(const float* __restrict__ x,
                                               unsigned short* __restrict__ xb) {
  __shared__ float tile[64][65];
  const int t = threadIdx.x;
  const int y = blockIdx.x, n = blockIdx.y;
  const float* xn = x + (size_t)n * 64 * 4096 + y * 64;
#pragma unroll
  for (int it = 0; it < 16; ++it) {
    int idx = it * 256 + t;
    int c = idx >> 6, xx = idx & 63;
    tile[c][xx] = xn[c * 4096 + xx];
  }
  __syncthreads();
  const int xx = t >> 2, cq = t & 3;
  unsigned short* dst = xb + ((size_t)n * 4096 + y * 64 + xx) * 64;
#pragma unroll
  for (int jj = 0; jj < 2; ++jj) {
    int ch0 = cq * 16 + jj * 8;
    unsigned int p[4];
#pragma unroll
    for (int e = 0; e < 4; ++e)
      p[e] = packbf2(tile[ch0 + e * 2][xx], tile[ch0 + e * 2 + 1][xx]);
    *(uint4*)&dst[ch0] = make_uint4(p[0], p[1], p[2], p[3]);
  }
}

// ---------------------------------------------------------------------------
// Fused conv1+BN+tanh -> h (LDS only) -> conv2+BN+tanh -> bc (global NHWC bf16)
// Block: 256 thr (4 waves), bc tile 16 wide x 8 tall. Grid (32, 16) = 512.
// h halo outside the image is ZERO (conv2 zero-padding semantics).
// B (weights) from swizzled fragment-order buffers: coalesced wave loads.
// ---------------------------------------------------------------------------
__global__ __launch_bounds__(256) void fused_conv(
    const unsigned short* __restrict__ xb, const unsigned short* __restrict__ w1swz,
    const unsigned short* __restrict__ w2swz, const float* __restrict__ b1,
    const float* __restrict__ g1, const float* __restrict__ be1,
    const float* __restrict__ m1, const float* __restrict__ v1,
    const float* __restrict__ b2, const float* __restrict__ g2,
    const float* __restrict__ be2, const float* __restrict__ m2,
    const float* __restrict__ v2, unsigned short* __restrict__ bcg) {
  __shared__ unsigned short xls[240 * 72];  // [(xr*20+xc)][ic]
  __shared__ unsigned short hls[192 * 72];  // [hpx][oc]

  const int t = threadIdx.x;
  const int tile = blockIdx.x, n = blockIdx.y;
  const int x0 = (tile & 3) * 16, y0 = (tile >> 2) * 8;

  // stage x: rows y0-2..y0+9, cols x0-2..x0+17
  const unsigned short* xbn = xb + (size_t)n * 4096 * 64;
#pragma unroll
  for (int it = 0; it < 8; ++it) {
    int idx = it * 256 + t;  // 1920 total
    if (idx < 1920) {
      int pos = idx >> 3, u4 = idx & 7;
      int xr = pos / 20, xc = pos - xr * 20;
      int gy = y0 - 2 + xr, gx = x0 - 2 + xc;
      uint4 v = {0u, 0u, 0u, 0u};
      if ((unsigned)gy < 64u && (unsigned)gx < 64u)
        v = *(const uint4*)&xbn[((size_t)gy * 64 + gx) * 64 + u4 * 8];
      *(uint4*)&xls[pos * 72 + u4 * 8] = v;
    }
  }
  __syncthreads();

  const int lane = t & 63, w = t >> 6;
  const int wm = w & 1, wn = w >> 1;
  const int lm = lane & 15, lq = lane >> 4;

  // ---- phase 1: h = tanh(bn1(conv1(x))), M=192(180 used), N=64, K=576 ----
  int abase[6];
#pragma unroll
  for (int i = 0; i < 6; ++i) {
    int m = wm + 2 * i;
    int px = m * 16 + lm;
    if (px > 179) px = 179;
    int r = px / 18, c = px - r * 18;
    abase[i] = (r * 20 + c) * 72 + lq * 8;
  }
  floatx4 acc[6][2];
#pragma unroll
  for (int i = 0; i < 6; ++i)
#pragma unroll
    for (int u = 0; u < 2; ++u) acc[i][u] = floatx4{0.f, 0.f, 0.f, 0.f};

#pragma unroll
  for (int step = 0; step < 18; ++step) {
    const int off = step >> 1, kc = step & 1;
    const int di = off / 3, dj = off % 3;
    short8 b[2];
#pragma unroll
    for (int u = 0; u < 2; ++u)
      b[u] = *(const short8*)&w1swz[(off * 512 + kc * 256 + wn * 128 + u * 64 +
                                     lane) * 8];
#pragma unroll
    for (int i = 0; i < 6; ++i) {
      short8 a = *(const short8*)&xls[abase[i] + (di * 20 + dj) * 72 + kc * 32];
      acc[i][0] = MFMA16(a, b[0], acc[i][0]);
      acc[i][1] = MFMA16(a, b[1], acc[i][1]);
    }
  }
  {
    float sc[2], sh[2];
#pragma unroll
    for (int u = 0; u < 2; ++u) {
      int oc = wn * 32 + u * 16 + lm;
      sc[u] = g1[oc] * rsqrtf(v1[oc] + 1e-5f);
      sh[u] = (b1[oc] - m1[oc]) * sc[u] + be1[oc];
    }
#pragma unroll
    for (int i = 0; i < 6; ++i) {
      int px0 = (wm + 2 * i) * 16 + lq * 4;
#pragma unroll
      for (int u = 0; u < 2; ++u) {
        int oc = wn * 32 + u * 16 + lm;
#pragma unroll
        for (int r = 0; r < 4; ++r) {
          int px = px0 + r;
          int rh = px / 18, ch = px - rh * 18;
          int gy = y0 - 1 + rh, gx = x0 - 1 + ch;
          bool valid = ((unsigned)gy < 64u) && ((unsigned)gx < 64u);
          float val = valid ? fast_tanh(acc[i][u][r] * sc[u] + sh[u]) : 0.f;
          hls[px * 72 + oc] = f2bf(val);
        }
      }
    }
  }
  __syncthreads();

  // ---- phase 2: bc = tanh(bn2(conv2(h))), M=128, N=96, K=576 ----
  int hbase[4];
#pragma unroll
  for (int i = 0; i < 4; ++i) {
    int opx = (wm + 2 * i) * 16 + lm;
    int br = opx >> 4, bcol = opx & 15;
    hbase[i] = (br * 18 + bcol) * 72 + lq * 8;
  }
  floatx4 acc2[4][3];
#pragma unroll
  for (int i = 0; i < 4; ++i)
#pragma unroll
    for (int u = 0; u < 3; ++u) acc2[i][u] = floatx4{0.f, 0.f, 0.f, 0.f};

#pragma unroll
  for (int step = 0; step < 18; ++step) {
    const int off = step >> 1, kc = step & 1;
    const int di = off / 3, dj = off % 3;
    short8 b[3];
#pragma unroll
    for (int u = 0; u < 3; ++u)
      b[u] = *(const short8*)&w2swz[(off * 768 + kc * 384 + wn * 192 + u * 64 +
                                     lane) * 8];
#pragma unroll
    for (int i = 0; i < 4; ++i) {
      short8 a = *(const short8*)&hls[hbase[i] + (di * 18 + dj) * 72 + kc * 32];
      acc2[i][0] = MFMA16(a, b[0], acc2[i][0]);
      acc2[i][1] = MFMA16(a, b[1], acc2[i][1]);
      acc2[i][2] = MFMA16(a, b[2], acc2[i][2]);
    }
  }
  {
    float sc[3], sh[3];
#pragma unroll
    for (int u = 0; u < 3; ++u) {
      int oc = wn * 48 + u * 16 + lm;
      sc[u] = g2[oc] * rsqrtf(v2[oc] + 1e-5f);
      sh[u] = (b2[oc] - m2[oc]) * sc[u] + be2[oc];
    }
    unsigned short* bcn = bcg + (size_t)n * 4096 * 96;
#pragma unroll
    for (int i = 0; i < 4; ++i) {
      int opx0 = (wm + 2 * i) * 16 + lq * 4;
#pragma unroll
      for (int u = 0; u < 3; ++u) {
        int oc = wn * 48 + u * 16 + lm;
#pragma unroll
        for (int r = 0; r < 4; ++r) {
          int opx = opx0 + r;
          int y = y0 + (opx >> 4), xx = x0 + (opx & 15);
          bcn[((size_t)y * 64 + xx) * 96 + oc] =
              f2bf(fast_tanh(acc2[i][u][r] * sc[u] + sh[u]));
        }
      }
    }
  }
}

// ---------------------------------------------------------------------------
// adconv v3b: barrier-free, swizzled B. Block 256 thr (4 waves), 8x8 px tile.
// Wave w owns px = w*16+lm, all 128 oc. atoms[9][8] in regs; patches via
// broadcast ds_read_b64; B frags contiguous in coefswz (coalesced 1KB loads).
// ---------------------------------------------------------------------------
__global__ __launch_bounds__(256) void adconv_final(
    const unsigned short* __restrict__ xb, const unsigned short* __restrict__ bc,
    const float* __restrict__ bases, const unsigned short* __restrict__ coefswz,
    float* __restrict__ out) {
  __shared__ unsigned short xs[100 * 72];  // [pos][c], 14.4 KB

  const int t = threadIdx.x;
  const int tile = blockIdx.x, n = blockIdx.y;
  const int q0 = (tile & 7) * 8, p0 = (tile >> 3) * 8;

  float bs[54];
#pragma unroll
  for (int i = 0; i < 54; ++i) bs[i] = bases[i];

  // stage xs[pos][c] from xb NHWC (coalesced uint4)
  const unsigned short* xbn = xb + (size_t)n * 4096 * 64;
#pragma unroll
  for (int it = 0; it < 4; ++it) {
    int idx = it * 256 + t;  // 800 total
    if (idx < 800) {
      int pos = idx >> 3, u4 = idx & 7;
      int r = pos / 10, col = pos - r * 10;
      int gp = p0 - 1 + r, gq = q0 - 1 + col;
      uint4 v = {0u, 0u, 0u, 0u};
      if ((unsigned)gp < 64u && (unsigned)gq < 64u)
        v = *(const uint4*)&xbn[((size_t)gp * 64 + gq) * 64 + u4 * 8];
      *(uint4*)&xs[pos * 72 + u4 * 8] = v;
    }
  }

  const int lane = t & 63, w = t >> 6;
  const int lm = lane & 15, lq = lane >> 4;
  const int px = w * 16 + lm;
  const int qx = px >> 3, py = px & 7;
  const int fh = lq & 1;               // f-half
  const unsigned sh = (lq >> 1) * 16;  // c half-select shift

  // atoms[k][j] for f = fh*8+j, from bc global (bf16 NHWC)
  float at[9][8];
  {
    const unsigned short* bp =
        bc + ((size_t)n * 4096 + (q0 + qx) * 64 + (p0 + py)) * 96 + fh * 48;
    float bcv[48];
#pragma unroll
    for (int m = 0; m < 6; ++m) {
      uint4 v = *(const uint4*)(bp + m * 8);
      unsigned int uu[4] = {v.x, v.y, v.z, v.w};
#pragma unroll
      for (int e = 0; e < 4; ++e) {
        bcv[m * 8 + e * 2] = bflo(uu[e]);
        bcv[m * 8 + e * 2 + 1] = bfhi(uu[e]);
      }
    }
#pragma unroll
    for (int j = 0; j < 8; ++j)
#pragma unroll
      for (int k = 0; k < 9; ++k) {
        float a = 0.f;
#pragma unroll
        for (int tt = 0; tt < 6; ++tt)
          a = fmaf(bcv[j * 6 + tt], bs[tt * 9 + k], a);
        at[k][j] = a;
      }
  }

  // patch base addresses (shorts)
  int pa[9];
#pragma unroll
  for (int i = 0; i < 3; ++i)
#pragma unroll
    for (int j = 0; j < 3; ++j)
      pa[i * 3 + j] = ((py + i) * 10 + qx + j) * 72;

  const unsigned short* cbase = coefswz + (size_t)lane * 8;

  __syncthreads();  // xs ready

  floatx4 acc[8];
#pragma unroll
  for (int u = 0; u < 8; ++u) acc[u] = floatx4{0.f, 0.f, 0.f, 0.f};

#pragma unroll
  for (int rd = 0; rd < 16; ++rd) {
    // patches: one b64 per pos gives the round's c-quad (broadcast across lq)
    uint2 q[9];
#pragma unroll
    for (int p = 0; p < 9; ++p) q[p] = *(const uint2*)&xs[pa[p] + rd * 4];
    float a0[8], a1[8];
#pragma unroll
    for (int j = 0; j < 8; ++j) { a0[j] = 0.f; a1[j] = 0.f; }
#pragma unroll
    for (int p = 0; p < 9; ++p) {
      float p0v = __uint_as_float((q[p].x >> sh) << 16);  // kc=0 patch
      float p1v = __uint_as_float((q[p].y >> sh) << 16);  // kc=1 patch
#pragma unroll
      for (int j = 0; j < 8; ++j) {
        a0[j] = fmaf(p0v, at[p][j], a0[j]);
        a1[j] = fmaf(p1v, at[p][j], a1[j]);
      }
    }
    short8 A0, A1;
    {
      unsigned int w0[4], w1[4];
#pragma unroll
      for (int e = 0; e < 4; ++e) {
        w0[e] = packbf2(a0[e * 2], a0[e * 2 + 1]);
        w1[e] = packbf2(a1[e * 2], a1[e * 2 + 1]);
      }
      uint4 t0 = make_uint4(w0[0], w0[1], w0[2], w0[3]);
      uint4 t1 = make_uint4(w1[0], w1[1], w1[2], w1[3]);
      A0 = *(short8*)&t0;
      A1 = *(short8*)&t1;
    }
    // B frags: contiguous fragment-order, frag = rd*1024 + kc*512 + u*64 + lane
#pragma unroll
    for (int u = 0; u < 8; ++u) {
      short8 b0 = *(const short8*)(cbase + (size_t)(rd * 1024 + u * 64) * 8);
      short8 b1 =
          *(const short8*)(cbase + (size_t)(rd * 1024 + 512 + u * 64) * 8);
      acc[u] = MFMA16(A0, b0, acc[u]);
      acc[u] = MFMA16(A1, b1, acc[u]);
    }
  }

  // direct stores: C/D reg-run is contiguous in p (fast axis)
  float* outn = out + (size_t)n * 128 * 4096;
  const int px0 = w * 16 + lq * 4;
  const int qxs = px0 >> 3, py0 = px0 & 7;
#pragma unroll
  for (int u = 0; u < 8; ++u) {
    int oc = u * 16 + lm;
    *(float4*)&outn[((size_t)oc * 64 + q0 + qxs) * 64 + p0 + py0] =
        make_float4(acc[u][0], acc[u][1], acc[u][2], acc[u][3]);
  }
}

// ---------------------------------------------------------------------------
extern "C" void kernel_launch(void* const* d_in, const int* in_sizes, int n_in,
                              void* d_out, int out_size, void* d_ws,
                              size_t ws_size, hipStream_t stream) {
  const float* x = (const float*)d_in[0];
  const float* conv1_w = (const float*)d_in[1];
  const float* conv1_b = (const float*)d_in[2];
  const float* bn1_g = (const float*)d_in[3];
  const float* bn1_b = (const float*)d_in[4];
  const float* bn1_m = (const float*)d_in[5];
  const float* bn1_v = (const float*)d_in[6];
  const float* conv2_w = (const float*)d_in[7];
  const float* conv2_b = (const float*)d_in[8];
  const float* bn2_g = (const float*)d_in[9];
  const float* bn2_b = (const float*)d_in[10];
  const float* bn2_m = (const float*)d_in[11];
  const float* bn2_v = (const float*)d_in[12];
  const float* bases = (const float*)d_in[13];
  const float* coef = (const float*)d_in[14];
  float* out = (float*)d_out;

  char* ws = (char*)d_ws;
  unsigned short* xbuf = (unsigned short*)(ws);             // 8,388,608 B
  unsigned short* bcb = (unsigned short*)(ws + 8388608);    // 12,582,912 B
  unsigned short* w1swz = (unsigned short*)(ws + 20971520); // 73,728 B
  unsigned short* w2swz = (unsigned short*)(ws + 21045248); // 110,592 B
  unsigned short* coefswz = (unsigned short*)(ws + 21155840); // 262,144 B

  prep_weights<<<512, 256, 0, stream>>>(conv1_w, conv2_w, coef, w1swz, w2swz,
                                        coefswz);
  xb_prep<<<dim3(64, NBATCH), 256, 0, stream>>>(x, xbuf);
  fused_conv<<<dim3(32, NBATCH), 256, 0, stream>>>(
      xbuf, w1swz, w2swz, conv1_b, bn1_g, bn1_b, bn1_m, bn1_v, conv2_b, bn2_g,
      bn2_b, bn2_m, bn2_v, bcb);
  adconv_final<<<dim3(64, NBATCH), 256, 0, stream>>>(xbuf, bcb, bases, coefswz,
                                                     out);
}

// Round 8
// 167.189 us; speedup vs baseline: 1.5329x; 1.1271x over previous
//
#include <hip/hip_runtime.h>
#include <math.h>
#include <string.h>

#define NBATCH 16

typedef __attribute__((ext_vector_type(8))) short short8;
typedef __attribute__((ext_vector_type(4))) float floatx4;
#define MFMA16(a, b, c) __builtin_amdgcn_mfma_f32_16x16x32_bf16(a, b, c, 0, 0, 0)

__device__ __forceinline__ unsigned short f2bf(float f) {
  unsigned int u = __float_as_uint(f);
  unsigned int rounding = ((u >> 16) & 1u) + 0x7fffu;
  return (unsigned short)((u + rounding) >> 16);
}
__device__ __forceinline__ unsigned int packbf2(float a, float b) {
  return (unsigned int)f2bf(a) | ((unsigned int)f2bf(b) << 16);
}
__device__ __forceinline__ float bflo(unsigned int u) {
  return __uint_as_float(u << 16);
}
__device__ __forceinline__ float bfhi(unsigned int u) {
  return __uint_as_float(u & 0xffff0000u);
}
__device__ __forceinline__ float fast_tanh(float x) {
  float e = __expf(2.f * x);
  return 1.f - 2.f / (e + 1.f);
}

// ---------------------------------------------------------------------------
// prep: fragment-order (swizzled) B layouts -> every wave B-load is one
// coalesced 1KB global_load_dwordx4.
//  coefswz: frag = ((rd*2+kc)*2+wj)*4+u  (rd<16,kc<2,wj<2,u<4), lane l:
//           coef[oc=wj*64+u*16+lm][k=rd*64+kc*32+lq*8+j]
//  w1swz:   frag = off*8 + kc*4 + wn*2 + u  -> w1[oc=wn*32+u*16+lm][ic=kc*32+lq*8+j][off]
//  w2swz:   frag = off*12 + kc*6 + wn*3 + u -> w2[oc=wn*48+u*16+lm][ic=kc*32+lq*8+j][off]
// ---------------------------------------------------------------------------
__global__ void prep_weights(const float* __restrict__ w1,
                             const float* __restrict__ w2,
                             const float* __restrict__ coef,
                             unsigned short* __restrict__ w1swz,
                             unsigned short* __restrict__ w2swz,
                             unsigned short* __restrict__ coefswz) {
  int i = blockIdx.x * 256 + threadIdx.x;
  if (i < 131072) {
    int j = i & 7, f = i >> 3;
    int lane = f & 63;
    int u = (f >> 6) & 3;
    int wj = (f >> 8) & 1;
    int kc = (f >> 9) & 1;
    int rd = f >> 10;
    int lm = lane & 15, lq = lane >> 4;
    int oc = wj * 64 + u * 16 + lm;
    int k = rd * 64 + kc * 32 + lq * 8 + j;
    coefswz[i] = f2bf(coef[oc * 1024 + k]);
  }
  if (i < 36864) {
    int j = i & 7, f = i >> 3;
    int lane = f & 63;
    int u = (f >> 6) & 1;
    int wn = (f >> 7) & 1;
    int kc = (f >> 8) & 1;
    int off = f >> 9;
    int lm = lane & 15, lq = lane >> 4;
    int oc = wn * 32 + u * 16 + lm;
    int ic = kc * 32 + lq * 8 + j;
    w1swz[i] = f2bf(w1[(oc * 64 + ic) * 9 + off]);
  }
  if (i < 55296) {
    int j = i & 7, f = i >> 3;
    int lane = f & 63;
    int rem = f >> 6;
    int u = rem % 3;
    int rem2 = rem / 3;
    int wn = rem2 & 1;
    int kc = (rem2 >> 1) & 1;
    int off = rem2 >> 2;
    int lm = lane & 15, lq = lane >> 4;
    int oc = wn * 48 + u * 16 + lm;
    int ic = kc * 32 + lq * 8 + j;
    w2swz[i] = f2bf(w2[(oc * 64 + ic) * 9 + off]);
  }
}

// ---------------------------------------------------------------------------
// x (fp32 NCHW) -> xb (bf16 NHWC), via LDS transpose. Block = (n, y) row.
// ---------------------------------------------------------------------------
__global__ __launch_bounds__(256) void xb_prep(const float* __restrict__ x,
                                               unsigned short* __restrict__ xb) {
  __shared__ float tile[64][65];
  const int t = threadIdx.x;
  const int y = blockIdx.x, n = blockIdx.y;
  const float* xn = x + (size_t)n * 64 * 4096 + y * 64;
#pragma unroll
  for (int it = 0; it < 16; ++it) {
    int idx = it * 256 + t;
    int c = idx >> 6, xx = idx & 63;
    tile[c][xx] = xn[c * 4096 + xx];
  }
  __syncthreads();
  const int xx = t >> 2, cq = t & 3;
  unsigned short* dst = xb + ((size_t)n * 4096 + y * 64 + xx) * 64;
#pragma unroll
  for (int jj = 0; jj < 2; ++jj) {
    int ch0 = cq * 16 + jj * 8;
    unsigned int p[4];
#pragma unroll
    for (int e = 0; e < 4; ++e)
      p[e] = packbf2(tile[ch0 + e * 2][xx], tile[ch0 + e * 2 + 1][xx]);
    *(uint4*)&dst[ch0] = make_uint4(p[0], p[1], p[2], p[3]);
  }
}

// ---------------------------------------------------------------------------
// Fused conv1+BN+tanh -> h (LDS) -> conv2+BN+tanh -> bc (global NHWC bf16)
// v2: 8x8 bc tile, grid (64, 16) = 1024 blocks (4/CU). LDS 39.2 KB.
// x region 12x12, h region 10x10 (alloc 128 pos; pads never read).
// h outside the image is ZERO (conv2 zero-padding semantics).
// ---------------------------------------------------------------------------
__global__ __launch_bounds__(256) void fused_conv(
    const unsigned short* __restrict__ xb, const unsigned short* __restrict__ w1swz,
    const unsigned short* __restrict__ w2swz, const float* __restrict__ b1,
    const float* __restrict__ g1, const float* __restrict__ be1,
    const float* __restrict__ m1, const float* __restrict__ v1,
    const float* __restrict__ b2, const float* __restrict__ g2,
    const float* __restrict__ be2, const float* __restrict__ m2,
    const float* __restrict__ v2, unsigned short* __restrict__ bcg) {
  __shared__ unsigned short xls[144 * 72];  // [(xr*12+xc)][ic]
  __shared__ unsigned short hls[128 * 72];  // [hr*10+hc][oc], 100 used

  const int t = threadIdx.x;
  const int tile = blockIdx.x, n = blockIdx.y;
  const int x0 = (tile & 7) * 8, y0 = (tile >> 3) * 8;

  // stage x: rows y0-2..y0+9, cols x0-2..x0+9
  const unsigned short* xbn = xb + (size_t)n * 4096 * 64;
#pragma unroll
  for (int it = 0; it < 5; ++it) {
    int idx = it * 256 + t;  // 1152 total
    if (idx < 1152) {
      int pos = idx >> 3, u4 = idx & 7;
      int xr = pos / 12, xc = pos - xr * 12;
      int gy = y0 - 2 + xr, gx = x0 - 2 + xc;
      uint4 v = {0u, 0u, 0u, 0u};
      if ((unsigned)gy < 64u && (unsigned)gx < 64u)
        v = *(const uint4*)&xbn[((size_t)gy * 64 + gx) * 64 + u4 * 8];
      *(uint4*)&xls[pos * 72 + u4 * 8] = v;
    }
  }
  __syncthreads();

  const int lane = t & 63, w = t >> 6;
  const int wm = w & 1, wn = w >> 1;
  const int lm = lane & 15, lq = lane >> 4;

  // ---- phase 1: h = tanh(bn1(conv1(x))), M=128 (100 used), N=64, K=576 ----
  int abase[4];
#pragma unroll
  for (int i = 0; i < 4; ++i) {
    int px = (wm + 2 * i) * 16 + lm;
    if (px > 99) px = 99;
    int hr = px / 10, hc = px - hr * 10;
    abase[i] = (hr * 12 + hc) * 72 + lq * 8;
  }
  floatx4 acc[4][2];
#pragma unroll
  for (int i = 0; i < 4; ++i)
#pragma unroll
    for (int u = 0; u < 2; ++u) acc[i][u] = floatx4{0.f, 0.f, 0.f, 0.f};

#pragma unroll
  for (int step = 0; step < 18; ++step) {
    const int off = step >> 1, kc = step & 1;
    const int di = off / 3, dj = off % 3;
    short8 b[2];
#pragma unroll
    for (int u = 0; u < 2; ++u)
      b[u] = *(const short8*)&w1swz[(off * 512 + kc * 256 + wn * 128 + u * 64 +
                                     lane) * 8];
#pragma unroll
    for (int i = 0; i < 4; ++i) {
      short8 a = *(const short8*)&xls[abase[i] + (di * 12 + dj) * 72 + kc * 32];
      acc[i][0] = MFMA16(a, b[0], acc[i][0]);
      acc[i][1] = MFMA16(a, b[1], acc[i][1]);
    }
  }
  {
    float sc[2], sh[2];
#pragma unroll
    for (int u = 0; u < 2; ++u) {
      int oc = wn * 32 + u * 16 + lm;
      sc[u] = g1[oc] * rsqrtf(v1[oc] + 1e-5f);
      sh[u] = (b1[oc] - m1[oc]) * sc[u] + be1[oc];
    }
#pragma unroll
    for (int i = 0; i < 4; ++i) {
      int px0 = (wm + 2 * i) * 16 + lq * 4;
#pragma unroll
      for (int u = 0; u < 2; ++u) {
        int oc = wn * 32 + u * 16 + lm;
#pragma unroll
        for (int r = 0; r < 4; ++r) {
          int px = px0 + r;
          if (px < 100) {
            int hr = px / 10, hc = px - hr * 10;
            int gy = y0 - 1 + hr, gx = x0 - 1 + hc;
            bool valid = ((unsigned)gy < 64u) && ((unsigned)gx < 64u);
            float val = valid ? fast_tanh(acc[i][u][r] * sc[u] + sh[u]) : 0.f;
            hls[px * 72 + oc] = f2bf(val);
          }
        }
      }
    }
  }
  __syncthreads();

  // ---- phase 2: bc = tanh(bn2(conv2(h))), M=64, N=96, K=576 ----
  int hbase[2];
#pragma unroll
  for (int s = 0; s < 2; ++s) {
    int opx = (wm + 2 * s) * 16 + lm;
    int yl = opx >> 3, xl = opx & 7;
    hbase[s] = (yl * 10 + xl) * 72 + lq * 8;
  }
  floatx4 acc2[2][3];
#pragma unroll
  for (int s = 0; s < 2; ++s)
#pragma unroll
    for (int u = 0; u < 3; ++u) acc2[s][u] = floatx4{0.f, 0.f, 0.f, 0.f};

#pragma unroll
  for (int step = 0; step < 18; ++step) {
    const int off = step >> 1, kc = step & 1;
    const int di = off / 3, dj = off % 3;
    short8 b[3];
#pragma unroll
    for (int u = 0; u < 3; ++u)
      b[u] = *(const short8*)&w2swz[(off * 768 + kc * 384 + wn * 192 + u * 64 +
                                     lane) * 8];
#pragma unroll
    for (int s = 0; s < 2; ++s) {
      short8 a = *(const short8*)&hls[hbase[s] + (di * 10 + dj) * 72 + kc * 32];
      acc2[s][0] = MFMA16(a, b[0], acc2[s][0]);
      acc2[s][1] = MFMA16(a, b[1], acc2[s][1]);
      acc2[s][2] = MFMA16(a, b[2], acc2[s][2]);
    }
  }
  {
    float sc[3], sh[3];
#pragma unroll
    for (int u = 0; u < 3; ++u) {
      int oc = wn * 48 + u * 16 + lm;
      sc[u] = g2[oc] * rsqrtf(v2[oc] + 1e-5f);
      sh[u] = (b2[oc] - m2[oc]) * sc[u] + be2[oc];
    }
    unsigned short* bcn = bcg + (size_t)n * 4096 * 96;
#pragma unroll
    for (int s = 0; s < 2; ++s) {
      int opx0 = (wm + 2 * s) * 16 + lq * 4;
#pragma unroll
      for (int u = 0; u < 3; ++u) {
        int oc = wn * 48 + u * 16 + lm;
#pragma unroll
        for (int r = 0; r < 4; ++r) {
          int opx = opx0 + r;
          int y = y0 + (opx >> 3), xx = x0 + (opx & 7);
          bcn[((size_t)y * 64 + xx) * 96 + oc] =
              f2bf(fast_tanh(acc2[s][u][r] * sc[u] + sh[u]));
        }
      }
    }
  }
}

// ---------------------------------------------------------------------------
// adconv v4: block = 128 px (16q x 8p), 4 waves split 2M x 2N (wave = 64px x
// 64oc) -> per-wave B traffic halved (256 MB total L2). A-tile through
// double-buffered LDS in MFMA-frag order; build lane = (px=t>>1, fh=t&1), no
// atom redundancy. Per rd: A/B frag loads issue before build(rd+1) VALU
// (explicit software pipeline), then 32 MFMA. 1 barrier/rd.
// ---------------------------------------------------------------------------
__global__ __launch_bounds__(256, 2) void adconv_final(
    const unsigned short* __restrict__ xb, const unsigned short* __restrict__ bc,
    const float* __restrict__ bases, const unsigned short* __restrict__ coefswz,
    float* __restrict__ out) {
  __shared__ unsigned short xs[180 * 72];  // [(row p)*18 + (col q)][c] 25.9 KB
  __shared__ uint4 As2[2 * 128 * 9];       // dbuf [px][8 units + pad] 36.9 KB

  const int t = threadIdx.x;
  const int tile = blockIdx.x, n = blockIdx.y;
  const int q0 = (tile & 3) * 16, p0 = (tile >> 2) * 8;

  float bs[54];
#pragma unroll
  for (int i = 0; i < 54; ++i) bs[i] = bases[i];

  // stage xs[pos][c]: rows p0-1..p0+8 (10), cols q0-1..q0+16 (18)
  const unsigned short* xbn = xb + (size_t)n * 4096 * 64;
#pragma unroll
  for (int it = 0; it < 6; ++it) {
    int idx = it * 256 + t;  // 1440 total
    if (idx < 1440) {
      int pos = idx >> 3, u4 = idx & 7;
      int row = pos / 18, col = pos - row * 18;
      int gp = p0 - 1 + row, gq = q0 - 1 + col;
      uint4 v = {0u, 0u, 0u, 0u};
      if ((unsigned)gp < 64u && (unsigned)gq < 64u)
        v = *(const uint4*)&xbn[((size_t)gp * 64 + gq) * 64 + u4 * 8];
      *(uint4*)&xs[pos * 72 + u4 * 8] = v;
    }
  }

  const int lane = t & 63, w = t >> 6;
  const int lm = lane & 15, lq = lane >> 4;
  const int wi = w & 1, wj = w >> 1;  // M-half, N-half

  // A-build role: px = t>>1, f-half = t&1
  const int px_a = t >> 1, fh = t & 1;
  const int qx_a = px_a >> 3, py_a = px_a & 7;

  // atoms[k][j] for f = fh*8+j (from bc global, bf16 NHWC)
  float at[9][8];
  {
    const unsigned short* bp =
        bc + ((size_t)n * 4096 + (q0 + qx_a) * 64 + (p0 + py_a)) * 96 + fh * 48;
    float bcv[48];
#pragma unroll
    for (int m = 0; m < 6; ++m) {
      uint4 v = *(const uint4*)(bp + m * 8);
      unsigned int uu[4] = {v.x, v.y, v.z, v.w};
#pragma unroll
      for (int e = 0; e < 4; ++e) {
        bcv[m * 8 + e * 2] = bflo(uu[e]);
        bcv[m * 8 + e * 2 + 1] = bfhi(uu[e]);
      }
    }
#pragma unroll
    for (int j = 0; j < 8; ++j)
#pragma unroll
      for (int k = 0; k < 9; ++k) {
        float a = 0.f;
#pragma unroll
        for (int tt = 0; tt < 6; ++tt)
          a = fmaf(bcv[j * 6 + tt], bs[tt * 9 + k], a);
        at[k][j] = a;
      }
  }

  int pa[9];
#pragma unroll
  for (int i = 0; i < 3; ++i)
#pragma unroll
    for (int j = 0; j < 3; ++j)
      pa[i * 3 + j] = ((py_a + i) * 18 + qx_a + j) * 72;

  floatx4 acc[4][4];
#pragma unroll
  for (int s = 0; s < 4; ++s)
#pragma unroll
    for (int u = 0; u < 4; ++u) acc[s][u] = floatx4{0.f, 0.f, 0.f, 0.f};

  // build K-chunk rd (4 c, 16 f -> 64 K-elems per px) into As2[buf]
  auto build = [&](int rd, int buf) {
    const int coff = rd * 4;
    uint2 q[9];
#pragma unroll
    for (int p = 0; p < 9; ++p) q[p] = *(const uint2*)&xs[pa[p] + coff];
    float a[4][8];
#pragma unroll
    for (int cc = 0; cc < 4; ++cc)
#pragma unroll
      for (int jj = 0; jj < 8; ++jj) a[cc][jj] = 0.f;
#pragma unroll
    for (int p = 0; p < 9; ++p) {
      float c0 = bflo(q[p].x), c1 = bfhi(q[p].x);
      float c2 = bflo(q[p].y), c3 = bfhi(q[p].y);
#pragma unroll
      for (int jj = 0; jj < 8; ++jj) {
        float av = at[p][jj];
        a[0][jj] = fmaf(c0, av, a[0][jj]);
        a[1][jj] = fmaf(c1, av, a[1][jj]);
        a[2][jj] = fmaf(c2, av, a[2][jj]);
        a[3][jj] = fmaf(c3, av, a[3][jj]);
      }
    }
    uint4* dst = &As2[buf * 1152 + px_a * 9];
#pragma unroll
    for (int cc = 0; cc < 4; ++cc) {
      int unit = (cc >> 1) * 4 + (cc & 1) * 2 + fh;
      dst[unit] = make_uint4(packbf2(a[cc][0], a[cc][1]),
                             packbf2(a[cc][2], a[cc][3]),
                             packbf2(a[cc][4], a[cc][5]),
                             packbf2(a[cc][6], a[cc][7]));
    }
  };

  __syncthreads();  // xs staged
  build(0, 0);
  __syncthreads();

  for (int rd = 0; rd < 16; ++rd) {
    const int buf = rd & 1;
    // frag loads for rd first (latency covered by build VALU below)
    short8 Af[4][2];
#pragma unroll
    for (int s = 0; s < 4; ++s) {
      int px = wi * 64 + s * 16 + lm;
#pragma unroll
      for (int kc = 0; kc < 2; ++kc)
        Af[s][kc] = *(const short8*)&As2[buf * 1152 + px * 9 + kc * 4 + lq];
    }
    short8 Bf[2][4];
#pragma unroll
    for (int kc = 0; kc < 2; ++kc)
#pragma unroll
      for (int u = 0; u < 4; ++u) {
        int frag = ((rd * 2 + kc) * 2 + wj) * 4 + u;
        Bf[kc][u] = *(const short8*)(coefswz + ((size_t)frag * 64 + lane) * 8);
      }
    if (rd < 15) build(rd + 1, buf ^ 1);
#pragma unroll
    for (int kc = 0; kc < 2; ++kc)
#pragma unroll
      for (int u = 0; u < 4; ++u)
#pragma unroll
        for (int s = 0; s < 4; ++s)
          acc[s][u] = MFMA16(Af[s][kc], Bf[kc][u], acc[s][u]);
    __syncthreads();
  }

  // epilogue: direct float4 stores (C/D reg-run contiguous along p)
  float* outn = out + (size_t)n * 128 * 4096;
#pragma unroll
  for (int u = 0; u < 4; ++u) {
    int oc = wj * 64 + u * 16 + lm;
#pragma unroll
    for (int s = 0; s < 4; ++s) {
      int px0 = wi * 64 + s * 16 + lq * 4;
      int qx = px0 >> 3, py0 = px0 & 7;
      *(float4*)&outn[((size_t)oc * 64 + q0 + qx) * 64 + p0 + py0] =
          make_float4(acc[s][u][0], acc[s][u][1], acc[s][u][2], acc[s][u][3]);
    }
  }
}

// ---------------------------------------------------------------------------
extern "C" void kernel_launch(void* const* d_in, const int* in_sizes, int n_in,
                              void* d_out, int out_size, void* d_ws,
                              size_t ws_size, hipStream_t stream) {
  const float* x = (const float*)d_in[0];
  const float* conv1_w = (const float*)d_in[1];
  const float* conv1_b = (const float*)d_in[2];
  const float* bn1_g = (const float*)d_in[3];
  const float* bn1_b = (const float*)d_in[4];
  const float* bn1_m = (const float*)d_in[5];
  const float* bn1_v = (const float*)d_in[6];
  const float* conv2_w = (const float*)d_in[7];
  const float* conv2_b = (const float*)d_in[8];
  const float* bn2_g = (const float*)d_in[9];
  const float* bn2_b = (const float*)d_in[10];
  const float* bn2_m = (const float*)d_in[11];
  const float* bn2_v = (const float*)d_in[12];
  const float* bases = (const float*)d_in[13];
  const float* coef = (const float*)d_in[14];
  float* out = (float*)d_out;

  char* ws = (char*)d_ws;
  unsigned short* xbuf = (unsigned short*)(ws);             // 8,388,608 B
  unsigned short* bcb = (unsigned short*)(ws + 8388608);    // 12,582,912 B
  unsigned short* w1swz = (unsigned short*)(ws + 20971520); // 73,728 B
  unsigned short* w2swz = (unsigned short*)(ws + 21045248); // 110,592 B
  unsigned short* coefswz = (unsigned short*)(ws + 21155840); // 262,144 B

  prep_weights<<<512, 256, 0, stream>>>(conv1_w, conv2_w, coef, w1swz, w2swz,
                                        coefswz);
  xb_prep<<<dim3(64, NBATCH), 256, 0, stream>>>(x, xbuf);
  fused_conv<<<dim3(64, NBATCH), 256, 0, stream>>>(
      xbuf, w1swz, w2swz, conv1_b, bn1_g, bn1_b, bn1_m, bn1_v, conv2_b, bn2_g,
      bn2_b, bn2_m, bn2_v, bcb);
  adconv_final<<<dim3(32, NBATCH), 256, 0, stream>>>(xbuf, bcb, bases, coefswz,
                                                     out);
}